// Round 16
// baseline (113.767 us; speedup 1.0000x reference)
//
#include <hip/hip_runtime.h>
#include <hip/hip_bf16.h>
#include <math.h>

#define B_  8
#define N_  1024
#define H_  512
#define NH_ 8
#define HD_ 64

typedef __attribute__((ext_vector_type(8))) short short8;
typedef __attribute__((ext_vector_type(4))) short short4_t;
typedef __attribute__((ext_vector_type(4))) float floatx4;

#define GPTR(p) ((const __attribute__((address_space(1))) void*)(p))
#define LPTR(p) ((__attribute__((address_space(3))) void*)(p))

// ds_read_b64_tr_b16: lane l elem j <- lds[region + j*16 + (l&15)] (bf16 elems)
#define TRB16(dst, addr, IMM) \
    asm volatile("ds_read_b64_tr_b16 %0, %1 offset:" IMM \
                 : "=v"(dst) : "v"(addr) : "memory")

#define EXP2(x) exp2f(x)
#define LOG2E 1.44269504088896f

static __device__ __forceinline__ unsigned short f2bf(float f) {
    __hip_bfloat16 h = __float2bfloat16(f);
    unsigned short u;
    __builtin_memcpy(&u, &h, 2);
    return u;
}

// ---------------------------------------------------------------------------
// prep: [blocks 0,1280): fp32->bf16 blob [xb | Wq | Wk | Wv | Wo]
//       [blocks 1280,3328): bins[b][q][k] = mask ? 255 : clip(d*10,0,49)
// ---------------------------------------------------------------------------
__global__ __launch_bounds__(256) void prep_kernel(
    const float* __restrict__ x,  const float* __restrict__ wq,
    const float* __restrict__ wk, const float* __restrict__ wv,
    const float* __restrict__ wo, unsigned short* __restrict__ dst,
    const float* __restrict__ dist, const int* __restrict__ mask,
    unsigned char* __restrict__ bins)
{
    const int bid = blockIdx.x;
    if (bid < 1280) {
        const int n4 = (4194304 + 4 * 262144) / 4;
        int i = bid * 256 + threadIdx.x;
        for (; i < n4; i += 1280 * 256) {
            const int e = i * 4;
            const float* src;
            if (e < 4194304) {
                src = x + e;
            } else {
                const int rel = e - 4194304;
                const int w = rel >> 18;
                const int off = rel & 262143;
                src = (w == 0 ? wq : w == 1 ? wk : w == 2 ? wv : wo) + off;
            }
            const float4 v = *(const float4*)src;
            ushort4 r;
            r.x = f2bf(v.x); r.y = f2bf(v.y); r.z = f2bf(v.z); r.w = f2bf(v.w);
            *(ushort4*)(dst + e) = r;
        }
    } else {
        const int gid = (bid - 1280) * 256 + threadIdx.x;   // 524288 total
        const size_t e = (size_t)gid * 16;
        const int b = gid >> 16;
        const int k = (gid & 63) * 16;
        const float* dsrc = dist + e;
        const int*   msrc = mask + b * N_ + k;
        unsigned w[4];
        #pragma unroll
        for (int i = 0; i < 4; ++i) {
            const float4 v = *(const float4*)(dsrc + 4 * i);
            const int4  mm = *(const int4*)(msrc + 4 * i);
            int b0 = (int)(v.x * 10.f); b0 = b0 < 0 ? 0 : (b0 > 49 ? 49 : b0);
            int b1 = (int)(v.y * 10.f); b1 = b1 < 0 ? 0 : (b1 > 49 ? 49 : b1);
            int b2 = (int)(v.z * 10.f); b2 = b2 < 0 ? 0 : (b2 > 49 ? 49 : b2);
            int b3 = (int)(v.w * 10.f); b3 = b3 < 0 ? 0 : (b3 > 49 ? 49 : b3);
            if (mm.x) b0 = 255;
            if (mm.y) b1 = 255;
            if (mm.z) b2 = 255;
            if (mm.w) b3 = 255;
            w[i] = (unsigned)b0 | ((unsigned)b1 << 8) | ((unsigned)b2 << 16) | ((unsigned)b3 << 24);
        }
        uint4 u; u.x = w[0]; u.y = w[1]; u.z = w[2]; u.w = w[3];
        *(uint4*)(bins + e) = u;
    }
}

// ---------------------------------------------------------------------------
// MFMA GEMM (m97 structure), unchanged.
// ---------------------------------------------------------------------------
template <int BF16OUT>
static __device__ __forceinline__ void gemm_core(
    const unsigned short* __restrict__ A, const unsigned short* __restrict__ W,
    const float* __restrict__ bias, void* __restrict__ C,
    int Ncols, int K, float scale, int row0, int col0)
{
    __shared__ unsigned short As[128 * 32];
    __shared__ unsigned short Bs[128 * 32];

    const int t    = threadIdx.x;
    const int lane = t & 63;
    const int wave = t >> 6;
    const int wr   = wave >> 1;
    const int wc   = wave & 1;
    const int l15  = lane & 15;
    const int lhi  = lane >> 4;

    const int srow = wave * 32 + (lane >> 2);
    const int sk   = (lane & 3) * 8;
    const unsigned short* gA = A + (size_t)(row0 + srow) * K + sk;
    const unsigned short* gB = W + (size_t)(col0 + srow) * K + sk;

    floatx4 acc[4][4];
    #pragma unroll
    for (int m = 0; m < 4; ++m)
        #pragma unroll
        for (int n = 0; n < 4; ++n) acc[m][n] = (floatx4)0.f;

    for (int k0 = 0; k0 < K; k0 += 32) {
        __syncthreads();
        #pragma unroll
        for (int i = 0; i < 2; ++i) {
            __builtin_amdgcn_global_load_lds(GPTR(gA + (size_t)(i * 16) * K + k0),
                                             LPTR(&As[(wave * 32 + i * 16) * 32]), 16, 0, 0);
            __builtin_amdgcn_global_load_lds(GPTR(gB + (size_t)(i * 16) * K + k0),
                                             LPTR(&Bs[(wave * 32 + i * 16) * 32]), 16, 0, 0);
        }
        __syncthreads();

        short8 af[4], bf[4];
        #pragma unroll
        for (int m = 0; m < 4; ++m)
            af[m] = *(const short8*)&As[(wr * 64 + m * 16 + l15) * 32 + lhi * 8];
        #pragma unroll
        for (int n = 0; n < 4; ++n)
            bf[n] = *(const short8*)&Bs[(wc * 64 + n * 16 + l15) * 32 + lhi * 8];
        #pragma unroll
        for (int m = 0; m < 4; ++m)
            #pragma unroll
            for (int n = 0; n < 4; ++n)
                acc[m][n] = __builtin_amdgcn_mfma_f32_16x16x32_bf16(af[m], bf[n], acc[m][n], 0, 0, 0);
    }

    #pragma unroll
    for (int n = 0; n < 4; ++n) {
        const int col = col0 + wc * 64 + n * 16 + l15;
        const float bvv = bias[col];
        #pragma unroll
        for (int m = 0; m < 4; ++m) {
            #pragma unroll
            for (int r = 0; r < 4; ++r) {
                const int row = row0 + wr * 64 + m * 16 + lhi * 4 + r;
                const float v = (acc[m][n][r] + bvv) * scale;
                if (BF16OUT)
                    ((unsigned short*)C)[(size_t)row * Ncols + col] = f2bf(v);
                else
                    ((float*)C)[(size_t)row * Ncols + col] = v;
            }
        }
    }
}

__global__ __launch_bounds__(256) void gemm_qkv(
    const unsigned short* __restrict__ xb,
    const unsigned short* __restrict__ Wq, const unsigned short* __restrict__ Wk,
    const unsigned short* __restrict__ Wv,
    const float* __restrict__ bq, const float* __restrict__ bk,
    const float* __restrict__ bv,
    unsigned short* __restrict__ Qb, unsigned short* __restrict__ Kb,
    unsigned short* __restrict__ Vb)
{
    const int z = blockIdx.z;
    const unsigned short* W = z == 0 ? Wq : (z == 1 ? Wk : Wv);
    const float* bias       = z == 0 ? bq : (z == 1 ? bk : bv);
    unsigned short* C       = z == 0 ? Qb : (z == 1 ? Kb : Vb);
    const float scale       = z == 0 ? (0.125f * LOG2E) : 1.0f;
    gemm_core<1>(xb, W, bias, C, H_, H_, scale, blockIdx.y * 128, blockIdx.x * 128);
}

__global__ __launch_bounds__(256) void gemm_out(
    const unsigned short* __restrict__ Ab, const unsigned short* __restrict__ Wo,
    const float* __restrict__ bo, float* __restrict__ out)
{
    gemm_core<0>(Ab, Wo, bo, out, H_, H_, 1.0f, blockIdx.y * 128, blockIdx.x * 128);
}

// ---------------------------------------------------------------------------
// MFMA flash attention — 8-wave 128-q blocks, KVBLK=128 (was 64).
// Halves per-k fixed costs: barriers/tile-count 32->16, softmax reduce +
// alpha-rescale passes x16 -> x8. PV runs as two k-64 half-passes so the
// per-wave P region stays 2KB. Single-buffered (dbuf was neutral, R15).
// LDS: Ks 16K + Vs 16K + QPs 16K + Bs 18K = 66.4KB -> 2 blocks/CU.
// ---------------------------------------------------------------------------
__global__ __launch_bounds__(512) void attn_mfma(
    const unsigned short* __restrict__ Qg, const unsigned short* __restrict__ Kg,
    const unsigned short* __restrict__ Vg, const unsigned char* __restrict__ bins,
    const float* __restrict__ demb, const float* __restrict__ abias,
    unsigned short* __restrict__ O)
{
    // ---- XCD swizzle (bijective; 512 = 8 XCD * 64) ----
    const int lin = blockIdx.x + 8 * blockIdx.y + 64 * blockIdx.z;
    const int swz = (lin & 7) * 64 + (lin >> 3);
    const int qt = swz & 7;          // 0..7 (128-q tiles)
    const int h  = (swz >> 3) & 7;
    const int b  = swz >> 6;
    const int q0 = qt * 128;
    const int t  = threadIdx.x;      // 0..511
    const int lane = t & 63;
    const int wave = t >> 6;         // 0..7
    const int l15 = lane & 15;
    const int lhi = lane >> 4;

    __shared__ unsigned short Ks[128 * 64];   // 16KB, XOR-swizzled rows
    __shared__ unsigned short Vs[128 * 64];   // 16KB, [d/16][k/4][4][16] subtiled
    __shared__ unsigned short QPs[128 * 64];  // 16KB: Q prologue, then 8x2KB P
    __shared__ unsigned char  Bs[128 * 144];  // 18KB: [q][k] bins tile

    // lane-register bias table (log2e domain); lane 63 = masked (-1.44e9)
    float dbl = -1.442695e9f;
    if (lane < 50) dbl = (demb[lane * NH_ + h] + abias[h]) * LOG2E;

    // ---- per-lane staging sources (pre-swizzled for linear LDS dest) ----
    // K/V tiles are 1024 16B-chunks; thread handles C0 = wave*128+lane, C0+64.
    const unsigned short* ksrc[2];
    const unsigned short* vsrc[2];
    #pragma unroll
    for (int i = 0; i < 2; ++i) {
        const int C = wave * 128 + i * 64 + lane;
        const int kr = C >> 3, kc = C & 7;
        ksrc[i] = Kg + ((size_t)(b * N_) + kr) * H_ + h * HD_ + ((kc ^ (kr & 7)) * 8);
        const int vd16 = C >> 8, vrem = C & 255;
        const int vkrhi = vrem >> 3, vr2 = vrem & 7;
        const int vkr = vkrhi * 4 + (vr2 >> 1), vcc = vr2 & 1;
        vsrc[i] = Vg + ((size_t)(b * N_) + vkr) * H_ + h * HD_ + vd16 * 16 + vcc * 8;
    }
    const unsigned char* bsrc = bins + ((size_t)(b * N_) + q0 + (t >> 2)) * N_ + (t & 3) * 16;
    const int bidx = (t >> 2) * 144 + (t & 3) * 16;

    // ---- stage Q (pre-scaled by 0.125*log2e), XOR-swizzled: 128 rows ----
    {
        const int qr = t >> 2;           // 0..127
        const int d0 = (t & 3) * 16;
        const unsigned short* src = Qg + ((size_t)(b * N_ + q0 + qr)) * H_ + h * HD_ + d0;
        #pragma unroll
        for (int cc = 0; cc < 2; ++cc) {
            const uint4 v = *(const uint4*)(src + 8 * cc);
            const int idx = (qr * 64 + d0 + 8 * cc) ^ ((qr & 7) << 3);
            *(uint4*)&QPs[idx] = v;
        }
    }
    __syncthreads();

    // Q fragment (B-operand of swapped QK^T; wave owns rows wave*16..+15)
    short8 aq[2];
    {
        const int qrow = (wave << 4) + l15;
        #pragma unroll
        for (int ck = 0; ck < 2; ++ck) {
            const int kb = lhi * 8 + 32 * ck;
            const int idx = (qrow * 64 + kb) ^ ((qrow & 7) << 3);
            aq[ck] = *(const short8*)&QPs[idx];
        }
    }
    __syncthreads();   // aq reads drained before QPs reused as P

    unsigned short* const Pw = &QPs[wave << 10];   // per-wave 2KB P region
    const unsigned trlane = (unsigned)(lhi << 8) + (unsigned)(l15 << 3);
    const unsigned vbase = (unsigned)(size_t)LPTR(&Vs[0]) + trlane;

    // per-lane softmax state for q = l15 (within this wave's 16-q group)
    float m = -INFINITY, lsum = 0.f;
    floatx4 o4[4];
    #pragma unroll
    for (int nd = 0; nd < 4; ++nd) o4[nd] = (floatx4)0.f;

    for (int tt = 0; tt < 8; ++tt) {
        const size_t koff = (size_t)(tt * 128);
        __syncthreads();   // previous tile's reads done
        {
            #pragma unroll
            for (int i = 0; i < 2; ++i) {
                __builtin_amdgcn_global_load_lds(GPTR(ksrc[i] + koff * H_),
                    LPTR(&Ks[(wave * 128 + i * 64) * 8]), 16, 0, 0);
                __builtin_amdgcn_global_load_lds(GPTR(vsrc[i] + koff * H_),
                    LPTR(&Vs[(wave * 128 + i * 64) * 8]), 16, 0, 0);
            }
            const uint4 b0v = *(const uint4*)(bsrc + koff);
            const uint4 b1v = *(const uint4*)(bsrc + koff + 64);
            *(uint4*)&Bs[bidx] = b0v;
            *(uint4*)&Bs[bidx + 64] = b1v;
        }
        __syncthreads();   // staging drained

        // ---- S^T over 128 k: s4[kn][r] = S[q=l15][k=kn*16+lhi*4+r] ----
        floatx4 s4[8];
        __builtin_amdgcn_s_setprio(1);
        #pragma unroll
        for (int kn = 0; kn < 8; ++kn) {
            const int kcol = kn * 16 + l15;
            floatx4 acc = (floatx4)0.f;
            #pragma unroll
            for (int ck = 0; ck < 2; ++ck) {
                const int kb = lhi * 8 + 32 * ck;
                const int idx = (kcol * 64 + kb) ^ ((kcol & 7) << 3);
                const short8 bk = *(const short8*)&Ks[idx];
                acc = __builtin_amdgcn_mfma_f32_16x16x32_bf16(bk, aq[ck], acc, 0, 0, 0);
            }
            s4[kn] = acc;
        }
        __builtin_amdgcn_s_setprio(0);

        // ---- + distance bias: row q=l15 (wave group), contiguous k per kn ----
        #pragma unroll
        for (int kn = 0; kn < 8; ++kn) {
            const unsigned bb =
                *(const unsigned*)&Bs[((wave << 4) + l15) * 144 + kn * 16 + (lhi << 2)];
            s4[kn][0] += __shfl(dbl, (int)(bb & 255u), 64);
            s4[kn][1] += __shfl(dbl, (int)((bb >> 8) & 255u), 64);
            s4[kn][2] += __shfl(dbl, (int)((bb >> 16) & 255u), 64);
            s4[kn][3] += __shfl(dbl, (int)(bb >> 24), 64);
        }

        // ---- online softmax over all 128 k (one reduce pass per tile) ----
        {
            float mx = s4[0][0];
            #pragma unroll
            for (int kn = 0; kn < 8; ++kn)
                #pragma unroll
                for (int r = 0; r < 4; ++r) mx = fmaxf(mx, s4[kn][r]);
            mx = fmaxf(mx, __shfl_xor(mx, 16, 64));
            mx = fmaxf(mx, __shfl_xor(mx, 32, 64));
            const float mnew = fmaxf(m, mx);
            float ts = 0.f;
            #pragma unroll
            for (int kn = 0; kn < 8; ++kn)
                #pragma unroll
                for (int r = 0; r < 4; ++r) {
                    const float pexp = EXP2(s4[kn][r] - mnew);
                    s4[kn][r] = pexp;
                    ts += pexp;
                }
            ts += __shfl_xor(ts, 16, 64);
            ts += __shfl_xor(ts, 32, 64);
            const float alpha = EXP2(m - mnew);
            lsum = lsum * alpha + ts;
            m = mnew;
            // broadcast alpha to O rows (q = lhi*4+r lives at lane l15=q)
            #pragma unroll
            for (int r = 0; r < 4; ++r) {
                const float ar = __shfl(alpha, lhi * 4 + r, 64);
                #pragma unroll
                for (int nd = 0; nd < 4; ++nd) o4[nd][r] *= ar;
            }
        }

        // ---- PV in two k-64 half-passes (P region stays 2KB/wave) ----
        #pragma unroll
        for (int ph = 0; ph < 2; ++ph) {
            // P[q=l15][k'] -> LDS: 4 b64 writes at contiguous k'
            #pragma unroll
            for (int kn = 0; kn < 4; ++kn) {
                const int kns = ph * 4 + kn;
                short4_t pk;
                pk[0] = (short)f2bf(s4[kns][0]);
                pk[1] = (short)f2bf(s4[kns][1]);
                pk[2] = (short)f2bf(s4[kns][2]);
                pk[3] = (short)f2bf(s4[kns][3]);
                const int idx = (l15 * 64 + kn * 16 + (lhi << 2)) ^ ((l15 & 7) << 3);
                *(short4_t*)&Pw[idx] = pk;
            }
            asm volatile("s_waitcnt lgkmcnt(0)" ::: "memory");
            __builtin_amdgcn_sched_barrier(0);

            // A = 2 direct b128 P reads; B = 16 V tr-reads for this half
            short8 ap[2];
            #pragma unroll
            for (int ck = 0; ck < 2; ++ck) {
                const int idx = (l15 * 64 + ck * 32 + lhi * 8) ^ ((l15 & 7) << 3);
                ap[ck] = *(const short8*)&Pw[idx];
            }
            const unsigned vaddr = vbase + (unsigned)(ph * 2048);
            short4_t v0l[4], v0h[4], v1l[4], v1h[4];
            TRB16(v0l[0], vaddr, "0");     TRB16(v0h[0], vaddr, "128");
            TRB16(v0l[1], vaddr, "4096");  TRB16(v0h[1], vaddr, "4224");
            TRB16(v0l[2], vaddr, "8192");  TRB16(v0h[2], vaddr, "8320");
            TRB16(v0l[3], vaddr, "12288"); TRB16(v0h[3], vaddr, "12416");
            TRB16(v1l[0], vaddr, "1024");  TRB16(v1h[0], vaddr, "1152");
            TRB16(v1l[1], vaddr, "5120");  TRB16(v1h[1], vaddr, "5248");
            TRB16(v1l[2], vaddr, "9216");  TRB16(v1h[2], vaddr, "9344");
            TRB16(v1l[3], vaddr, "13312"); TRB16(v1h[3], vaddr, "13440");
            asm volatile("s_waitcnt lgkmcnt(0)" ::: "memory");
            __builtin_amdgcn_sched_barrier(0);

            __builtin_amdgcn_s_setprio(1);
            #pragma unroll
            for (int nd = 0; nd < 4; ++nd) {
                const short8 bv0 = __builtin_shufflevector(v0l[nd], v0h[nd], 0, 1, 2, 3, 4, 5, 6, 7);
                o4[nd] = __builtin_amdgcn_mfma_f32_16x16x32_bf16(ap[0], bv0, o4[nd], 0, 0, 0);
                const short8 bv1 = __builtin_shufflevector(v1l[nd], v1h[nd], 0, 1, 2, 3, 4, 5, 6, 7);
                o4[nd] = __builtin_amdgcn_mfma_f32_16x16x32_bf16(ap[1], bv1, o4[nd], 0, 0, 0);
            }
            __builtin_amdgcn_s_setprio(0);
        }
    }

    // ---- epilogue: pull lsum for q=lhi*4+r, normalize, write ----
    float inv[4];
    #pragma unroll
    for (int r = 0; r < 4; ++r) inv[r] = 1.f / __shfl(lsum, lhi * 4 + r, 64);
    #pragma unroll
    for (int nd = 0; nd < 4; ++nd) {
        const int d = nd * 16 + l15;
        #pragma unroll
        for (int r = 0; r < 4; ++r) {
            const int q = q0 + (wave << 4) + lhi * 4 + r;
            O[((size_t)(b * N_ + q)) * H_ + h * HD_ + d] = f2bf(o4[nd][r] * inv[r]);
        }
    }
}

// ---------------------------------------------------------------------------
extern "C" void kernel_launch(void* const* d_in, const int* in_sizes, int n_in,
                              void* d_out, int out_size, void* d_ws, size_t ws_size,
                              hipStream_t stream)
{
    const float* x    = (const float*)d_in[0];
    const float* dist = (const float*)d_in[1];
    const int*   mask = (const int*)d_in[2];
    const float* Wq   = (const float*)d_in[3];
    const float* bq   = (const float*)d_in[4];
    const float* Wk   = (const float*)d_in[5];
    const float* bk   = (const float*)d_in[6];
    const float* Wv   = (const float*)d_in[7];
    const float* bv   = (const float*)d_in[8];
    const float* Wo   = (const float*)d_in[9];
    const float* bo   = (const float*)d_in[10];
    const float* demb = (const float*)d_in[11];
    const float* ab   = (const float*)d_in[12];
    float* out = (float*)d_out;

    const size_t mat = (size_t)B_ * N_ * H_;         // 4,194,304
    const size_t wsz = (size_t)H_ * H_;              //   262,144

    unsigned short* blob = (unsigned short*)d_ws;
    unsigned short* xb  = blob;
    unsigned short* Wqb = blob + mat;
    unsigned short* Wkb = Wqb + wsz;
    unsigned short* Wvb = Wkb + wsz;
    unsigned short* Wob = Wvb + wsz;
    unsigned short* Qb  = Wob + wsz;
    unsigned short* Kb  = Qb + mat;
    unsigned short* Vb  = Kb + mat;
    unsigned short* Ab  = Vb + mat;
    unsigned char*  binsb = (unsigned char*)(Ab + mat);

    const dim3 blk(256);

    hipLaunchKernelGGL(prep_kernel, dim3(3328), blk, 0, stream,
                       x, Wq, Wk, Wv, Wo, blob, dist, mask, binsb);

    const dim3 qgrid(H_ / 128, (B_ * N_) / 128, 3);
    hipLaunchKernelGGL(gemm_qkv, qgrid, blk, 0, stream,
                       xb, Wqb, Wkb, Wvb, bq, bk, bv, Qb, Kb, Vb);

    const dim3 agrid(N_ / 128, NH_, B_);             // (8, 8, 8) = 512 blocks
    hipLaunchKernelGGL(attn_mfma, agrid, dim3(512), 0, stream,
                       Qb, Kb, Vb, binsb, demb, ab, Ab);

    const dim3 ogrid(H_ / 128, (B_ * N_) / 128, 1);
    hipLaunchKernelGGL(gemm_out, ogrid, blk, 0, stream, Ab, Wob, bo, out);
}

// Round 17
// 102.517 us; speedup vs baseline: 1.1097x; 1.1097x over previous
//
#include <hip/hip_runtime.h>
#include <hip/hip_bf16.h>
#include <math.h>

#define B_  8
#define N_  1024
#define H_  512
#define NH_ 8
#define HD_ 64

typedef __attribute__((ext_vector_type(8))) short short8;
typedef __attribute__((ext_vector_type(4))) short short4_t;
typedef __attribute__((ext_vector_type(4))) float floatx4;

#define GPTR(p) ((const __attribute__((address_space(1))) void*)(p))
#define LPTR(p) ((__attribute__((address_space(3))) void*)(p))

// ds_read_b64_tr_b16: lane l elem j <- lds[region + j*16 + (l&15)] (bf16 elems)
#define TRB16(dst, addr, IMM) \
    asm volatile("ds_read_b64_tr_b16 %0, %1 offset:" IMM \
                 : "=v"(dst) : "v"(addr) : "memory")

#define EXP2(x) exp2f(x)
#define LOG2E 1.44269504088896f

static __device__ __forceinline__ unsigned short f2bf(float f) {
    __hip_bfloat16 h = __float2bfloat16(f);
    unsigned short u;
    __builtin_memcpy(&u, &h, 2);
    return u;
}

// ---------------------------------------------------------------------------
// prep: [blocks 0,1280): fp32->bf16 blob [xb | Wq | Wk | Wv | Wo]
//       [blocks 1280,3328): bins[b][q][k] = mask ? 255 : clip(d*10,0,49)
// ---------------------------------------------------------------------------
__global__ __launch_bounds__(256) void prep_kernel(
    const float* __restrict__ x,  const float* __restrict__ wq,
    const float* __restrict__ wk, const float* __restrict__ wv,
    const float* __restrict__ wo, unsigned short* __restrict__ dst,
    const float* __restrict__ dist, const int* __restrict__ mask,
    unsigned char* __restrict__ bins)
{
    const int bid = blockIdx.x;
    if (bid < 1280) {
        const int n4 = (4194304 + 4 * 262144) / 4;
        int i = bid * 256 + threadIdx.x;
        for (; i < n4; i += 1280 * 256) {
            const int e = i * 4;
            const float* src;
            if (e < 4194304) {
                src = x + e;
            } else {
                const int rel = e - 4194304;
                const int w = rel >> 18;
                const int off = rel & 262143;
                src = (w == 0 ? wq : w == 1 ? wk : w == 2 ? wv : wo) + off;
            }
            const float4 v = *(const float4*)src;
            ushort4 r;
            r.x = f2bf(v.x); r.y = f2bf(v.y); r.z = f2bf(v.z); r.w = f2bf(v.w);
            *(ushort4*)(dst + e) = r;
        }
    } else {
        const int gid = (bid - 1280) * 256 + threadIdx.x;   // 524288 total
        const size_t e = (size_t)gid * 16;
        const int b = gid >> 16;
        const int k = (gid & 63) * 16;
        const float* dsrc = dist + e;
        const int*   msrc = mask + b * N_ + k;
        unsigned w[4];
        #pragma unroll
        for (int i = 0; i < 4; ++i) {
            const float4 v = *(const float4*)(dsrc + 4 * i);
            const int4  mm = *(const int4*)(msrc + 4 * i);
            int b0 = (int)(v.x * 10.f); b0 = b0 < 0 ? 0 : (b0 > 49 ? 49 : b0);
            int b1 = (int)(v.y * 10.f); b1 = b1 < 0 ? 0 : (b1 > 49 ? 49 : b1);
            int b2 = (int)(v.z * 10.f); b2 = b2 < 0 ? 0 : (b2 > 49 ? 49 : b2);
            int b3 = (int)(v.w * 10.f); b3 = b3 < 0 ? 0 : (b3 > 49 ? 49 : b3);
            if (mm.x) b0 = 255;
            if (mm.y) b1 = 255;
            if (mm.z) b2 = 255;
            if (mm.w) b3 = 255;
            w[i] = (unsigned)b0 | ((unsigned)b1 << 8) | ((unsigned)b2 << 16) | ((unsigned)b3 << 24);
        }
        uint4 u; u.x = w[0]; u.y = w[1]; u.z = w[2]; u.w = w[3];
        *(uint4*)(bins + e) = u;
    }
}

// ---------------------------------------------------------------------------
// MFMA GEMM (m97 structure), unchanged.
// ---------------------------------------------------------------------------
template <int BF16OUT>
static __device__ __forceinline__ void gemm_core(
    const unsigned short* __restrict__ A, const unsigned short* __restrict__ W,
    const float* __restrict__ bias, void* __restrict__ C,
    int Ncols, int K, float scale, int row0, int col0)
{
    __shared__ unsigned short As[128 * 32];
    __shared__ unsigned short Bs[128 * 32];

    const int t    = threadIdx.x;
    const int lane = t & 63;
    const int wave = t >> 6;
    const int wr   = wave >> 1;
    const int wc   = wave & 1;
    const int l15  = lane & 15;
    const int lhi  = lane >> 4;

    const int srow = wave * 32 + (lane >> 2);
    const int sk   = (lane & 3) * 8;
    const unsigned short* gA = A + (size_t)(row0 + srow) * K + sk;
    const unsigned short* gB = W + (size_t)(col0 + srow) * K + sk;

    floatx4 acc[4][4];
    #pragma unroll
    for (int m = 0; m < 4; ++m)
        #pragma unroll
        for (int n = 0; n < 4; ++n) acc[m][n] = (floatx4)0.f;

    for (int k0 = 0; k0 < K; k0 += 32) {
        __syncthreads();
        #pragma unroll
        for (int i = 0; i < 2; ++i) {
            __builtin_amdgcn_global_load_lds(GPTR(gA + (size_t)(i * 16) * K + k0),
                                             LPTR(&As[(wave * 32 + i * 16) * 32]), 16, 0, 0);
            __builtin_amdgcn_global_load_lds(GPTR(gB + (size_t)(i * 16) * K + k0),
                                             LPTR(&Bs[(wave * 32 + i * 16) * 32]), 16, 0, 0);
        }
        __syncthreads();

        short8 af[4], bf[4];
        #pragma unroll
        for (int m = 0; m < 4; ++m)
            af[m] = *(const short8*)&As[(wr * 64 + m * 16 + l15) * 32 + lhi * 8];
        #pragma unroll
        for (int n = 0; n < 4; ++n)
            bf[n] = *(const short8*)&Bs[(wc * 64 + n * 16 + l15) * 32 + lhi * 8];
        #pragma unroll
        for (int m = 0; m < 4; ++m)
            #pragma unroll
            for (int n = 0; n < 4; ++n)
                acc[m][n] = __builtin_amdgcn_mfma_f32_16x16x32_bf16(af[m], bf[n], acc[m][n], 0, 0, 0);
    }

    #pragma unroll
    for (int n = 0; n < 4; ++n) {
        const int col = col0 + wc * 64 + n * 16 + l15;
        const float bvv = bias[col];
        #pragma unroll
        for (int m = 0; m < 4; ++m) {
            #pragma unroll
            for (int r = 0; r < 4; ++r) {
                const int row = row0 + wr * 64 + m * 16 + lhi * 4 + r;
                const float v = (acc[m][n][r] + bvv) * scale;
                if (BF16OUT)
                    ((unsigned short*)C)[(size_t)row * Ncols + col] = f2bf(v);
                else
                    ((float*)C)[(size_t)row * Ncols + col] = v;
            }
        }
    }
}

__global__ __launch_bounds__(256) void gemm_qkv(
    const unsigned short* __restrict__ xb,
    const unsigned short* __restrict__ Wq, const unsigned short* __restrict__ Wk,
    const unsigned short* __restrict__ Wv,
    const float* __restrict__ bq, const float* __restrict__ bk,
    const float* __restrict__ bv,
    unsigned short* __restrict__ Qb, unsigned short* __restrict__ Kb,
    unsigned short* __restrict__ Vb)
{
    const int z = blockIdx.z;
    const unsigned short* W = z == 0 ? Wq : (z == 1 ? Wk : Wv);
    const float* bias       = z == 0 ? bq : (z == 1 ? bk : bv);
    unsigned short* C       = z == 0 ? Qb : (z == 1 ? Kb : Vb);
    const float scale       = z == 0 ? (0.125f * LOG2E) : 1.0f;
    gemm_core<1>(xb, W, bias, C, H_, H_, scale, blockIdx.y * 128, blockIdx.x * 128);
}

__global__ __launch_bounds__(256) void gemm_out(
    const unsigned short* __restrict__ Ab, const unsigned short* __restrict__ Wo,
    const float* __restrict__ bo, float* __restrict__ out)
{
    gemm_core<0>(Ab, Wo, bo, out, H_, H_, 1.0f, blockIdx.y * 128, blockIdx.x * 128);
}

// ---------------------------------------------------------------------------
// MFMA flash attention — R15 best config (reverted from KVBLK=128 regression).
// 8 waves / 128-q blocks, KVBLK=64, double-buffered async staging, XCD
// swizzle, swapped-QK^T lane-local softmax, P b64/b128 round-trip, V tr-reads.
// ---------------------------------------------------------------------------
__global__ __launch_bounds__(512) void attn_mfma(
    const unsigned short* __restrict__ Qg, const unsigned short* __restrict__ Kg,
    const unsigned short* __restrict__ Vg, const unsigned char* __restrict__ bins,
    const float* __restrict__ demb, const float* __restrict__ abias,
    unsigned short* __restrict__ O)
{
    // ---- XCD swizzle (bijective; 512 = 8 XCD * 64) ----
    const int lin = blockIdx.x + 8 * blockIdx.y + 64 * blockIdx.z;
    const int swz = (lin & 7) * 64 + (lin >> 3);
    const int qt = swz & 7;          // 0..7 (128-q tiles)
    const int h  = (swz >> 3) & 7;
    const int b  = swz >> 6;
    const int q0 = qt * 128;
    const int t  = threadIdx.x;      // 0..511
    const int lane = t & 63;
    const int wave = t >> 6;         // 0..7
    const int l15 = lane & 15;
    const int lhi = lane >> 4;

    __shared__ unsigned short Ks[2][64 * 64];    // 2x8KB, XOR-swizzled rows
    __shared__ unsigned short Vs[2][64 * 64];    // 2x8KB, subtiled
    __shared__ unsigned short QPs[128 * 64];     // 16KB: Q prologue, then 8x2KB P
    __shared__ unsigned char  Bsh[2][128 * 80];  // 2x10KB: [q][k] bins tile

    // lane-register bias table (log2e domain); lane 63 = masked (-1.44e9)
    float dbl = -1.442695e9f;
    if (lane < 50) dbl = (demb[lane * NH_ + h] + abias[h]) * LOG2E;

    // ---- per-lane staging sources (pre-swizzled for linear LDS dest) ----
    const int C = wave * 64 + lane;
    const int kr = C >> 3, kc = C & 7;
    const unsigned short* ksrc =
        Kg + ((size_t)(b * N_) + kr) * H_ + h * HD_ + ((kc ^ (kr & 7)) * 8);
    const int vd16 = C >> 7, vrem = C & 127;
    const int vkrhi = vrem >> 3, vr2 = vrem & 7;
    const int vkr = vkrhi * 4 + (vr2 >> 1), vcc = vr2 & 1;
    const unsigned short* vsrc =
        Vg + ((size_t)(b * N_) + vkr) * H_ + h * HD_ + vd16 * 16 + vcc * 8;
    const unsigned char* bsrc = bins + ((size_t)(b * N_) + q0 + (t >> 2)) * N_ + (t & 3) * 16;
    const int bidx = (t >> 2) * 80 + (t & 3) * 16;

    // ---- stage Q (pre-scaled by 0.125*log2e), XOR-swizzled: 128 rows ----
    {
        const int qr = t >> 2;           // 0..127
        const int d0 = (t & 3) * 16;
        const unsigned short* src = Qg + ((size_t)(b * N_ + q0 + qr)) * H_ + h * HD_ + d0;
        #pragma unroll
        for (int cc = 0; cc < 2; ++cc) {
            const uint4 v = *(const uint4*)(src + 8 * cc);
            const int idx = (qr * 64 + d0 + 8 * cc) ^ ((qr & 7) << 3);
            *(uint4*)&QPs[idx] = v;
        }
    }
    // ---- tile-0 staging: bins reg first, then K/V direct-to-LDS ----
    const uint4 br0 = *(const uint4*)bsrc;
    __builtin_amdgcn_global_load_lds(GPTR(ksrc), LPTR(&Ks[0][(wave * 64) * 8]), 16, 0, 0);
    __builtin_amdgcn_global_load_lds(GPTR(vsrc), LPTR(&Vs[0][(wave * 64) * 8]), 16, 0, 0);
    __syncthreads();   // Q visible; tile-0 K/V landed

    // Q fragment (B-operand of swapped QK^T; wave owns rows wave*16..+15)
    short8 aq[2];
    {
        const int qrow = (wave << 4) + l15;
        #pragma unroll
        for (int ck = 0; ck < 2; ++ck) {
            const int kb = lhi * 8 + 32 * ck;
            const int idx = (qrow * 64 + kb) ^ ((qrow & 7) << 3);
            aq[ck] = *(const short8*)&QPs[idx];
        }
    }
    *(uint4*)&Bsh[0][bidx] = br0;
    __syncthreads();   // aq reads drained before QPs reused as P; Bsh[0] visible

    unsigned short* const Pw = &QPs[wave << 10];   // per-wave 2KB P region
    const unsigned trlane = (unsigned)(lhi << 8) + (unsigned)(l15 << 3);
    const unsigned vbase = (unsigned)(size_t)LPTR(&Vs[0][0]) + trlane;

    // per-lane softmax state for q = l15 (within this wave's 16-q group)
    float m = -INFINITY, lsum = 0.f;
    floatx4 o4[4];
    #pragma unroll
    for (int nd = 0; nd < 4; ++nd) o4[nd] = (floatx4)0.f;

    int p = 0;
    for (int tt = 0; tt < 16; ++tt) {
        // ---- issue tile t+1 staging into buf 1-p (bins reg-load FIRST) ----
        uint4 brn;
        if (tt < 15) {
            const size_t koff = (size_t)((tt + 1) * 64);
            brn = *(const uint4*)(bsrc + koff);
            __builtin_amdgcn_global_load_lds(GPTR(ksrc + koff * H_),
                LPTR(&Ks[1 - p][(wave * 64) * 8]), 16, 0, 0);
            __builtin_amdgcn_global_load_lds(GPTR(vsrc + koff * H_),
                LPTR(&Vs[1 - p][(wave * 64) * 8]), 16, 0, 0);
        }
        const unsigned short* Kp = &Ks[p][0];

        // ---- S^T = K (Q*0.125*log2e)^T : s4[kn][r] = S[q=l15][k=kn*16+lhi*4+r]
        floatx4 s4[4];
        __builtin_amdgcn_s_setprio(1);
        #pragma unroll
        for (int kn = 0; kn < 4; ++kn) {
            const int kcol = kn * 16 + l15;
            floatx4 acc = (floatx4)0.f;
            #pragma unroll
            for (int ck = 0; ck < 2; ++ck) {
                const int kb = lhi * 8 + 32 * ck;
                const int idx = (kcol * 64 + kb) ^ ((kcol & 7) << 3);
                const short8 bk = *(const short8*)&Kp[idx];
                acc = __builtin_amdgcn_mfma_f32_16x16x32_bf16(bk, aq[ck], acc, 0, 0, 0);
            }
            s4[kn] = acc;
        }
        __builtin_amdgcn_s_setprio(0);

        // ---- + distance bias: row q=l15 (wave group), contiguous k per kn ----
        #pragma unroll
        for (int kn = 0; kn < 4; ++kn) {
            const unsigned bb =
                *(const unsigned*)&Bsh[p][((wave << 4) + l15) * 80 + kn * 16 + (lhi << 2)];
            s4[kn][0] += __shfl(dbl, (int)(bb & 255u), 64);
            s4[kn][1] += __shfl(dbl, (int)((bb >> 8) & 255u), 64);
            s4[kn][2] += __shfl(dbl, (int)((bb >> 16) & 255u), 64);
            s4[kn][3] += __shfl(dbl, (int)(bb >> 24), 64);
        }

        // ---- online softmax: lane-local over 16 regs + 2-level shfl ----
        {
            float mx = s4[0][0];
            #pragma unroll
            for (int kn = 0; kn < 4; ++kn)
                #pragma unroll
                for (int r = 0; r < 4; ++r) mx = fmaxf(mx, s4[kn][r]);
            mx = fmaxf(mx, __shfl_xor(mx, 16, 64));
            mx = fmaxf(mx, __shfl_xor(mx, 32, 64));
            const float mnew = fmaxf(m, mx);
            float ts = 0.f;
            #pragma unroll
            for (int kn = 0; kn < 4; ++kn)
                #pragma unroll
                for (int r = 0; r < 4; ++r) {
                    const float pexp = EXP2(s4[kn][r] - mnew);
                    s4[kn][r] = pexp;
                    ts += pexp;
                }
            ts += __shfl_xor(ts, 16, 64);
            ts += __shfl_xor(ts, 32, 64);
            const float alpha = EXP2(m - mnew);
            lsum = lsum * alpha + ts;
            m = mnew;
            // broadcast alpha to O rows (q = lhi*4+r lives at lane l15=q)
            #pragma unroll
            for (int r = 0; r < 4; ++r) {
                const float ar = __shfl(alpha, lhi * 4 + r, 64);
                #pragma unroll
                for (int nd = 0; nd < 4; ++nd) o4[nd][r] *= ar;
            }
        }

        // ---- P[q=l15][k] -> LDS: 4 b64 writes at contiguous k ----
        #pragma unroll
        for (int kn = 0; kn < 4; ++kn) {
            short4_t pk;
            pk[0] = (short)f2bf(s4[kn][0]);
            pk[1] = (short)f2bf(s4[kn][1]);
            pk[2] = (short)f2bf(s4[kn][2]);
            pk[3] = (short)f2bf(s4[kn][3]);
            const int idx = (l15 * 64 + kn * 16 + (lhi << 2)) ^ ((l15 & 7) << 3);
            *(short4_t*)&Pw[idx] = pk;
        }

        // ---- PV: A = 2 direct b128 P reads; B = 16 V tr-reads ----
        short8 ap[2];
        #pragma unroll
        for (int ck = 0; ck < 2; ++ck) {
            const int idx = (l15 * 64 + ck * 32 + lhi * 8) ^ ((l15 & 7) << 3);
            ap[ck] = *(const short8*)&Pw[idx];
        }
        const unsigned vaddr = vbase + (unsigned)(p * 8192);
        short4_t v0l[4], v0h[4], v1l[4], v1h[4];
        TRB16(v0l[0], vaddr, "0");    TRB16(v0h[0], vaddr, "128");
        TRB16(v0l[1], vaddr, "2048"); TRB16(v0h[1], vaddr, "2176");
        TRB16(v0l[2], vaddr, "4096"); TRB16(v0h[2], vaddr, "4224");
        TRB16(v0l[3], vaddr, "6144"); TRB16(v0h[3], vaddr, "6272");
        TRB16(v1l[0], vaddr, "1024"); TRB16(v1h[0], vaddr, "1152");
        TRB16(v1l[1], vaddr, "3072"); TRB16(v1h[1], vaddr, "3200");
        TRB16(v1l[2], vaddr, "5120"); TRB16(v1h[2], vaddr, "5248");
        TRB16(v1l[3], vaddr, "7168"); TRB16(v1h[3], vaddr, "7296");
        asm volatile("s_waitcnt lgkmcnt(0)" ::: "memory");
        __builtin_amdgcn_sched_barrier(0);

        __builtin_amdgcn_s_setprio(1);
        #pragma unroll
        for (int nd = 0; nd < 4; ++nd) {
            const short8 bv0 = __builtin_shufflevector(v0l[nd], v0h[nd], 0, 1, 2, 3, 4, 5, 6, 7);
            o4[nd] = __builtin_amdgcn_mfma_f32_16x16x32_bf16(ap[0], bv0, o4[nd], 0, 0, 0);
            const short8 bv1 = __builtin_shufflevector(v1l[nd], v1h[nd], 0, 1, 2, 3, 4, 5, 6, 7);
            o4[nd] = __builtin_amdgcn_mfma_f32_16x16x32_bf16(ap[1], bv1, o4[nd], 0, 0, 0);
        }
        __builtin_amdgcn_s_setprio(0);

        // ---- bins t+1 -> alternate Bsh; ONE barrier drains staging ----
        if (tt < 15)
            *(uint4*)&Bsh[1 - p][bidx] = brn;
        __syncthreads();
        p ^= 1;
    }

    // ---- epilogue: pull lsum for q=lhi*4+r, normalize, write ----
    float inv[4];
    #pragma unroll
    for (int r = 0; r < 4; ++r) inv[r] = 1.f / __shfl(lsum, lhi * 4 + r, 64);
    #pragma unroll
    for (int nd = 0; nd < 4; ++nd) {
        const int d = nd * 16 + l15;
        #pragma unroll
        for (int r = 0; r < 4; ++r) {
            const int q = q0 + (wave << 4) + lhi * 4 + r;
            O[((size_t)(b * N_ + q)) * H_ + h * HD_ + d] = f2bf(o4[nd][r] * inv[r]);
        }
    }
}

// ---------------------------------------------------------------------------
extern "C" void kernel_launch(void* const* d_in, const int* in_sizes, int n_in,
                              void* d_out, int out_size, void* d_ws, size_t ws_size,
                              hipStream_t stream)
{
    const float* x    = (const float*)d_in[0];
    const float* dist = (const float*)d_in[1];
    const int*   mask = (const int*)d_in[2];
    const float* Wq   = (const float*)d_in[3];
    const float* bq   = (const float*)d_in[4];
    const float* Wk   = (const float*)d_in[5];
    const float* bk   = (const float*)d_in[6];
    const float* Wv   = (const float*)d_in[7];
    const float* bv   = (const float*)d_in[8];
    const float* Wo   = (const float*)d_in[9];
    const float* bo   = (const float*)d_in[10];
    const float* demb = (const float*)d_in[11];
    const float* ab   = (const float*)d_in[12];
    float* out = (float*)d_out;

    const size_t mat = (size_t)B_ * N_ * H_;         // 4,194,304
    const size_t wsz = (size_t)H_ * H_;              //   262,144

    unsigned short* blob = (unsigned short*)d_ws;
    unsigned short* xb  = blob;
    unsigned short* Wqb = blob + mat;
    unsigned short* Wkb = Wqb + wsz;
    unsigned short* Wvb = Wkb + wsz;
    unsigned short* Wob = Wvb + wsz;
    unsigned short* Qb  = Wob + wsz;
    unsigned short* Kb  = Qb + mat;
    unsigned short* Vb  = Kb + mat;
    unsigned short* Ab  = Vb + mat;
    unsigned char*  binsb = (unsigned char*)(Ab + mat);

    const dim3 blk(256);

    hipLaunchKernelGGL(prep_kernel, dim3(3328), blk, 0, stream,
                       x, Wq, Wk, Wv, Wo, blob, dist, mask, binsb);

    const dim3 qgrid(H_ / 128, (B_ * N_) / 128, 3);
    hipLaunchKernelGGL(gemm_qkv, qgrid, blk, 0, stream,
                       xb, Wqb, Wkb, Wvb, bq, bk, bv, Qb, Kb, Vb);

    const dim3 agrid(N_ / 128, NH_, B_);             // (8, 8, 8) = 512 blocks
    hipLaunchKernelGGL(attn_mfma, agrid, dim3(512), 0, stream,
                       Qb, Kb, Vb, binsb, demb, ab, Ab);

    const dim3 ogrid(H_ / 128, (B_ * N_) / 128, 1);
    hipLaunchKernelGGL(gemm_out, ogrid, blk, 0, stream, Ab, Wob, bo, out);
}